// Round 1
// baseline (15288.545 us; speedup 1.0000x reference)
//
#include <hip/hip_runtime.h>

// LightGCN propagation on MI355X.
// Inputs (per reference setup_inputs order):
//   d_in[0] user_indices (1024 int, UNUSED by reference output)
//   d_in[1] item_indices (1024 int, UNUSED)
//   d_in[2] adj_src  (6,000,000 int32)
//   d_in[3] adj_dst  (6,000,000 int32)
//   d_in[4] adj_vals (6,000,000 fp32)
//   d_in[5] user_emb (100000*64 fp32)
//   d_in[6] item_emb (50000*64 fp32)
// Output: [150000*64] fp32 = mean over (1+3) layer embeddings.
//
// Workspace layout: ws0 = cur buffer (38.4 MB), ws1 = next buffer (38.4 MB).
// acc lives directly in d_out. Ping-pong: L0 ws0->ws1, L1 ws1->ws0, L2 ws0->ws1.

#define NUM_USERS 100000
#define NUM_ITEMS 50000
#define N_NODES   150000
#define EMB       64
#define N_EDGES   6000000

constexpr int NODE_F4 = N_NODES * EMB / 4;   // 2,400,000 float4 per node matrix
constexpr int USER_F4 = NUM_USERS * EMB / 4; // 1,600,000

// init: cur = concat(user_emb, item_emb); acc = same; next = 0
__global__ void lgcn_init(const float4* __restrict__ user_emb,
                          const float4* __restrict__ item_emb,
                          float4* __restrict__ cur,
                          float4* __restrict__ nxt,
                          float4* __restrict__ acc) {
    int i = blockIdx.x * blockDim.x + threadIdx.x;
    if (i >= NODE_F4) return;
    float4 v = (i < USER_F4) ? user_emb[i] : item_emb[i - USER_F4];
    cur[i] = v;
    acc[i] = v;
    nxt[i] = make_float4(0.f, 0.f, 0.f, 0.f);
}

// scatter: 16 threads per edge, each owns one float4 (4 channels) of the row.
// next[dst] += val * cur[src]  via HW fp32 atomics.
__global__ void lgcn_scatter(const int* __restrict__ src,
                             const int* __restrict__ dst,
                             const float* __restrict__ val,
                             const float4* __restrict__ cur,
                             float* __restrict__ nxt) {
    int tid = blockIdx.x * blockDim.x + threadIdx.x;
    int e = tid >> 4;
    if (e >= N_EDGES) return;
    int c = tid & 15;                      // which float4 of the 64-wide row
    int s = src[e];
    int d = dst[e];
    float v = val[e];
    float4 m = cur[(long)s * 16 + c];      // coalesced 256B per edge across 16 lanes
    float* p = nxt + (long)d * 64 + c * 4;
    unsafeAtomicAdd(p + 0, v * m.x);
    unsafeAtomicAdd(p + 1, v * m.y);
    unsafeAtomicAdd(p + 2, v * m.z);
    unsafeAtomicAdd(p + 3, v * m.w);
}

// acc += nxt; zero the *other* buffer (which becomes the next layer's target)
__global__ void lgcn_add_zero(float4* __restrict__ acc,
                              const float4* __restrict__ nxt,
                              float4* __restrict__ other) {
    int i = blockIdx.x * blockDim.x + threadIdx.x;
    if (i >= NODE_F4) return;
    float4 a = acc[i];
    float4 n = nxt[i];
    a.x += n.x; a.y += n.y; a.z += n.z; a.w += n.w;
    acc[i] = a;
    other[i] = make_float4(0.f, 0.f, 0.f, 0.f);
}

// final: acc = (acc + nxt) * 0.25
__global__ void lgcn_final(float4* __restrict__ acc,
                           const float4* __restrict__ nxt) {
    int i = blockIdx.x * blockDim.x + threadIdx.x;
    if (i >= NODE_F4) return;
    float4 a = acc[i];
    float4 n = nxt[i];
    a.x = (a.x + n.x) * 0.25f;
    a.y = (a.y + n.y) * 0.25f;
    a.z = (a.z + n.z) * 0.25f;
    a.w = (a.w + n.w) * 0.25f;
    acc[i] = a;
}

extern "C" void kernel_launch(void* const* d_in, const int* in_sizes, int n_in,
                              void* d_out, int out_size, void* d_ws, size_t ws_size,
                              hipStream_t stream) {
    const int*   adj_src  = (const int*)d_in[2];
    const int*   adj_dst  = (const int*)d_in[3];
    const float* adj_vals = (const float*)d_in[4];
    const float4* user_emb = (const float4*)d_in[5];
    const float4* item_emb = (const float4*)d_in[6];

    float* acc = (float*)d_out;
    float* ws0 = (float*)d_ws;                       // cur for layer 0
    float* ws1 = ws0 + (size_t)N_NODES * EMB;        // next for layer 0

    const int BLK = 256;
    const int grid_node = (NODE_F4 + BLK - 1) / BLK;             // 9375
    const int grid_edge = (N_EDGES * 16 + BLK - 1) / BLK;        // 375000

    // init: ws0 = all_emb, acc = all_emb, ws1 = 0
    lgcn_init<<<grid_node, BLK, 0, stream>>>(user_emb, item_emb,
                                             (float4*)ws0, (float4*)ws1,
                                             (float4*)acc);

    // Layer 0: ws0 -> ws1 ; acc += ws1 ; zero ws0
    lgcn_scatter<<<grid_edge, BLK, 0, stream>>>(adj_src, adj_dst, adj_vals,
                                                (const float4*)ws0, ws1);
    lgcn_add_zero<<<grid_node, BLK, 0, stream>>>((float4*)acc, (const float4*)ws1,
                                                 (float4*)ws0);

    // Layer 1: ws1 -> ws0 ; acc += ws0 ; zero ws1
    lgcn_scatter<<<grid_edge, BLK, 0, stream>>>(adj_src, adj_dst, adj_vals,
                                                (const float4*)ws1, ws0);
    lgcn_add_zero<<<grid_node, BLK, 0, stream>>>((float4*)acc, (const float4*)ws0,
                                                 (float4*)ws1);

    // Layer 2: ws0 -> ws1 ; acc = (acc + ws1) * 0.25
    lgcn_scatter<<<grid_edge, BLK, 0, stream>>>(adj_src, adj_dst, adj_vals,
                                                (const float4*)ws0, ws1);
    lgcn_final<<<grid_node, BLK, 0, stream>>>((float4*)acc, (const float4*)ws1);
}

// Round 2
// 1317.811 us; speedup vs baseline: 11.6015x; 11.6015x over previous
//
#include <hip/hip_runtime.h>

// LightGCN propagation on MI355X — R1: device-built CSR + gather SpMM (no fp32 atomics).
//
// R0 post-mortem: scatter with fp32 atomics = 5.04 ms/layer, WRITE_SIZE 6.1 GB/layer
// (4x line-eviction amplification in L2), VALUBusy 1%. Fix: sort edges by dst once
// per call (histogram + scan + place), then gather-SpMM with coalesced row writes.
//
// Inputs: [2] adj_src (6M int), [3] adj_dst (6M int), [4] adj_vals (6M f32),
//         [5] user_emb (100000x64 f32), [6] item_emb (50000x64 f32).
// Output: [150000x64] f32 = (e0+e1+e2+e3)/4.

#define NUM_USERS 100000
#define NUM_ITEMS 50000
#define N_NODES   150000
#define EMB       64
#define N_EDGES   6000000

constexpr int NODE_F4 = N_NODES * EMB / 4;   // 2,400,000 float4
constexpr int USER_F4 = NUM_USERS * EMB / 4;
#define SCAN_BLK 256
constexpr int NBLK_CNT = (N_NODES + SCAN_BLK - 1) / SCAN_BLK;  // 586

// ---------------- CSR build ----------------

__global__ void k_zero_cnt(int* __restrict__ cnt) {
    int i = blockIdx.x * blockDim.x + threadIdx.x;
    if (i < N_NODES) cnt[i] = 0;
}

__global__ void k_hist(const int* __restrict__ dst, int* __restrict__ cnt) {
    int e = blockIdx.x * blockDim.x + threadIdx.x;
    if (e < N_EDGES) atomicAdd(&cnt[dst[e]], 1);
}

__global__ void k_blocksum(const int* __restrict__ cnt, int* __restrict__ bsum) {
    __shared__ int s[SCAN_BLK];
    int i = blockIdx.x * SCAN_BLK + threadIdx.x;
    s[threadIdx.x] = (i < N_NODES) ? cnt[i] : 0;
    __syncthreads();
    for (int off = SCAN_BLK / 2; off > 0; off >>= 1) {
        if (threadIdx.x < off) s[threadIdx.x] += s[threadIdx.x + off];
        __syncthreads();
    }
    if (threadIdx.x == 0) bsum[blockIdx.x] = s[0];
}

// single block of 1024: exclusive scan of NBLK_CNT block sums
__global__ void k_scan_bsum(const int* __restrict__ bsum, int* __restrict__ boff) {
    __shared__ int s[1024];
    int t = threadIdx.x;
    int x = (t < NBLK_CNT) ? bsum[t] : 0;
    s[t] = x;
    __syncthreads();
    for (int off = 1; off < 1024; off <<= 1) {
        int v = (t >= off) ? s[t - off] : 0;
        __syncthreads();
        s[t] += v;
        __syncthreads();
    }
    if (t < NBLK_CNT) boff[t] = s[t] - x;  // exclusive
}

__global__ void k_scan_final(const int* __restrict__ cnt, const int* __restrict__ boff,
                             int* __restrict__ row_ptr, int* __restrict__ cursor) {
    __shared__ int s[SCAN_BLK];
    int i = blockIdx.x * SCAN_BLK + threadIdx.x;
    int x = (i < N_NODES) ? cnt[i] : 0;
    s[threadIdx.x] = x;
    __syncthreads();
    for (int off = 1; off < SCAN_BLK; off <<= 1) {
        int v = (threadIdx.x >= off) ? s[threadIdx.x - off] : 0;
        __syncthreads();
        s[threadIdx.x] += v;
        __syncthreads();
    }
    if (i < N_NODES) {
        int ex = s[threadIdx.x] - x + boff[blockIdx.x];
        row_ptr[i] = ex;
        cursor[i]  = ex;
    }
    if (i == 0) row_ptr[N_NODES] = N_EDGES;
}

__global__ void k_place(const int* __restrict__ src, const int* __restrict__ dst,
                        const float* __restrict__ val,
                        int* __restrict__ cursor, int2* __restrict__ pairs) {
    int e = blockIdx.x * blockDim.x + threadIdx.x;
    if (e >= N_EDGES) return;
    int d = dst[e];
    int pos = atomicAdd(&cursor[d], 1);
    pairs[pos] = make_int2(src[e], __float_as_int(val[e]));
}

// ---------------- propagation ----------------

__global__ void k_init(const float4* __restrict__ ue, const float4* __restrict__ ie,
                       float4* __restrict__ cur, float4* __restrict__ acc) {
    int i = blockIdx.x * blockDim.x + threadIdx.x;
    if (i >= NODE_F4) return;
    float4 v = (i < USER_F4) ? ue[i] : ie[i - USER_F4];
    cur[i] = v;
    acc[i] = v;
}

// 16 lanes per dst row; each lane owns one float4 (4 channels).
// next[d] = sum_k val_k * cur[src_k];  acc = (acc + next) * s
__global__ void k_spmm(const int* __restrict__ row_ptr, const int2* __restrict__ pairs,
                       const float4* __restrict__ cur, float4* __restrict__ nxt,
                       float4* __restrict__ acc, float s) {
    int tid = blockIdx.x * blockDim.x + threadIdx.x;
    int row = tid >> 4;
    if (row >= N_NODES) return;
    int c = tid & 15;
    int beg = row_ptr[row];
    int end = row_ptr[row + 1];
    float4 r = make_float4(0.f, 0.f, 0.f, 0.f);
    int k = beg;
    // 2x unroll: issue both pair loads, then both gathers, to overlap latency
    for (; k + 1 < end; k += 2) {
        int2 p0 = pairs[k];
        int2 p1 = pairs[k + 1];
        float4 m0 = cur[(long)p0.x * 16 + c];
        float4 m1 = cur[(long)p1.x * 16 + c];
        float v0 = __int_as_float(p0.y);
        float v1 = __int_as_float(p1.y);
        r.x += v0 * m0.x + v1 * m1.x;
        r.y += v0 * m0.y + v1 * m1.y;
        r.z += v0 * m0.z + v1 * m1.z;
        r.w += v0 * m0.w + v1 * m1.w;
    }
    if (k < end) {
        int2 p0 = pairs[k];
        float4 m0 = cur[(long)p0.x * 16 + c];
        float v0 = __int_as_float(p0.y);
        r.x += v0 * m0.x;
        r.y += v0 * m0.y;
        r.z += v0 * m0.z;
        r.w += v0 * m0.w;
    }
    long o = (long)row * 16 + c;
    nxt[o] = r;
    float4 a = acc[o];
    a.x = (a.x + r.x) * s;
    a.y = (a.y + r.y) * s;
    a.z = (a.z + r.z) * s;
    a.w = (a.w + r.w) * s;
    acc[o] = a;
}

// ---------------- R0 fallback (atomic scatter) for small ws ----------------

__global__ void lgcn_init(const float4* __restrict__ user_emb,
                          const float4* __restrict__ item_emb,
                          float4* __restrict__ cur, float4* __restrict__ nxt,
                          float4* __restrict__ acc) {
    int i = blockIdx.x * blockDim.x + threadIdx.x;
    if (i >= NODE_F4) return;
    float4 v = (i < USER_F4) ? user_emb[i] : item_emb[i - USER_F4];
    cur[i] = v; acc[i] = v; nxt[i] = make_float4(0.f, 0.f, 0.f, 0.f);
}

__global__ void lgcn_scatter(const int* __restrict__ src, const int* __restrict__ dst,
                             const float* __restrict__ val,
                             const float4* __restrict__ cur, float* __restrict__ nxt) {
    int tid = blockIdx.x * blockDim.x + threadIdx.x;
    int e = tid >> 4;
    if (e >= N_EDGES) return;
    int c = tid & 15;
    int s = src[e]; int d = dst[e]; float v = val[e];
    float4 m = cur[(long)s * 16 + c];
    float* p = nxt + (long)d * 64 + c * 4;
    unsafeAtomicAdd(p + 0, v * m.x);
    unsafeAtomicAdd(p + 1, v * m.y);
    unsafeAtomicAdd(p + 2, v * m.z);
    unsafeAtomicAdd(p + 3, v * m.w);
}

__global__ void lgcn_add_zero(float4* __restrict__ acc, const float4* __restrict__ nxt,
                              float4* __restrict__ other) {
    int i = blockIdx.x * blockDim.x + threadIdx.x;
    if (i >= NODE_F4) return;
    float4 a = acc[i]; float4 n = nxt[i];
    a.x += n.x; a.y += n.y; a.z += n.z; a.w += n.w;
    acc[i] = a;
    other[i] = make_float4(0.f, 0.f, 0.f, 0.f);
}

__global__ void lgcn_final(float4* __restrict__ acc, const float4* __restrict__ nxt) {
    int i = blockIdx.x * blockDim.x + threadIdx.x;
    if (i >= NODE_F4) return;
    float4 a = acc[i]; float4 n = nxt[i];
    a.x = (a.x + n.x) * 0.25f; a.y = (a.y + n.y) * 0.25f;
    a.z = (a.z + n.z) * 0.25f; a.w = (a.w + n.w) * 0.25f;
    acc[i] = a;
}

// ---------------- launch ----------------

extern "C" void kernel_launch(void* const* d_in, const int* in_sizes, int n_in,
                              void* d_out, int out_size, void* d_ws, size_t ws_size,
                              hipStream_t stream) {
    const int*    adj_src  = (const int*)d_in[2];
    const int*    adj_dst  = (const int*)d_in[3];
    const float*  adj_vals = (const float*)d_in[4];
    const float4* user_emb = (const float4*)d_in[5];
    const float4* item_emb = (const float4*)d_in[6];
    float* acc = (float*)d_out;

    const int BLK = 256;
    const int grid_node = (NODE_F4 + BLK - 1) / BLK;      // 9375
    const int grid_edge = (N_EDGES + BLK - 1) / BLK;      // 23438
    const int grid_row16 = (N_NODES * 16 + BLK - 1) / BLK; // 9375

    // workspace layout (bytes)
    const size_t SZ_NODE  = (size_t)N_NODES * EMB * sizeof(float);  // 38,400,000
    const size_t SZ_PAIRS = (size_t)N_EDGES * 8;                    // 48,000,000
    const size_t SZ_RP    = (size_t)(N_NODES + 1) * sizeof(int);
    const size_t SZ_CUR   = (size_t)N_NODES * sizeof(int);
    const size_t SZ_B     = (size_t)NBLK_CNT * sizeof(int);
    const size_t NEEDED = 2 * SZ_NODE + SZ_PAIRS + SZ_RP + SZ_CUR + 2 * SZ_B + 64;

    if (ws_size >= NEEDED) {
        char* w = (char*)d_ws;
        float* cur    = (float*)(w);
        float* nxt    = (float*)(w + SZ_NODE);
        int2*  pairs  = (int2*)(w + 2 * SZ_NODE);
        int*   row_ptr= (int*)(w + 2 * SZ_NODE + SZ_PAIRS);
        int*   cursor = (int*)(w + 2 * SZ_NODE + SZ_PAIRS + SZ_RP);
        int*   bsum   = (int*)(w + 2 * SZ_NODE + SZ_PAIRS + SZ_RP + SZ_CUR);
        int*   boff   = (int*)(w + 2 * SZ_NODE + SZ_PAIRS + SZ_RP + SZ_CUR + SZ_B);
        int*   cnt    = row_ptr;  // reuse row_ptr[0..N_NODES) as the histogram buffer

        // CSR build. NOTE: cnt aliases row_ptr; k_scan_final reads cnt[i] and writes
        // row_ptr[i] at the same index AFTER the read — safe within a thread, and the
        // scan only reads its own block's values staged in LDS before any write.
        k_zero_cnt<<<NBLK_CNT, BLK, 0, stream>>>(cnt);
        k_hist<<<grid_edge, BLK, 0, stream>>>(adj_dst, cnt);
        k_blocksum<<<NBLK_CNT, BLK, 0, stream>>>(cnt, bsum);
        k_scan_bsum<<<1, 1024, 0, stream>>>(bsum, boff);
        k_scan_final<<<NBLK_CNT, BLK, 0, stream>>>(cnt, boff, row_ptr, cursor);
        k_place<<<grid_edge, BLK, 0, stream>>>(adj_src, adj_dst, adj_vals, cursor, pairs);

        // propagation
        k_init<<<grid_node, BLK, 0, stream>>>(user_emb, item_emb, (float4*)cur, (float4*)acc);
        k_spmm<<<grid_row16, BLK, 0, stream>>>(row_ptr, pairs, (const float4*)cur,
                                               (float4*)nxt, (float4*)acc, 1.0f);
        k_spmm<<<grid_row16, BLK, 0, stream>>>(row_ptr, pairs, (const float4*)nxt,
                                               (float4*)cur, (float4*)acc, 1.0f);
        k_spmm<<<grid_row16, BLK, 0, stream>>>(row_ptr, pairs, (const float4*)cur,
                                               (float4*)nxt, (float4*)acc, 0.25f);
    } else {
        // R0 fallback: atomic scatter (ws too small for CSR build)
        float* ws0 = (float*)d_ws;
        float* ws1 = ws0 + (size_t)N_NODES * EMB;
        lgcn_init<<<grid_node, BLK, 0, stream>>>(user_emb, item_emb,
                                                 (float4*)ws0, (float4*)ws1, (float4*)acc);
        lgcn_scatter<<<(N_EDGES*16+BLK-1)/BLK, BLK, 0, stream>>>(adj_src, adj_dst, adj_vals,
                                                    (const float4*)ws0, ws1);
        lgcn_add_zero<<<grid_node, BLK, 0, stream>>>((float4*)acc, (const float4*)ws1, (float4*)ws0);
        lgcn_scatter<<<(N_EDGES*16+BLK-1)/BLK, BLK, 0, stream>>>(adj_src, adj_dst, adj_vals,
                                                    (const float4*)ws1, ws0);
        lgcn_add_zero<<<grid_node, BLK, 0, stream>>>((float4*)acc, (const float4*)ws0, (float4*)ws1);
        lgcn_scatter<<<(N_EDGES*16+BLK-1)/BLK, BLK, 0, stream>>>(adj_src, adj_dst, adj_vals,
                                                    (const float4*)ws0, ws1);
        lgcn_final<<<grid_node, BLK, 0, stream>>>((float4*)acc, (const float4*)ws1);
    }
}